// Round 5
// baseline (377.672 us; speedup 1.0000x reference)
//
#include <hip/hip_runtime.h>

// Problem constants (from reference)
constexpr int B = 4, N = 1024, M = 64, H = 32, W = 32;
constexpr int HW = H * W;                     // 1024 floats = 4 KB = one chunk
constexpr int BN = B * N;                     // 4096
constexpr size_t S = (size_t)BN * HW;         // 4,194,304 floats (16 MiB)
constexpr float EXPAND   = 1.2f;
constexpr float TWO_SIG2 = 2.0f * 1.6f * 1.6f;
constexpr float THR2 = 0.6f;                  // GAUSS_THR
constexpr float THR3 = 0.5f;                  // GAUSS_3D_THR == GAUSS_DEPTH_THR
constexpr int GRID_B = 2048;                  // writer blocks (8/CU)
constexpr int NCHUNK = 81920;                 // total 4 KB chunks in output
constexpr int ITERS  = NCHUNK / GRID_B;       // 40

// d_ws layout: [0, S) score plane (BN x 1024 f32, 16 MiB); [S, S + BN*16) params
// params per bn (16 floats): kx, ky, validf, hasf, depth, d0, d1, d2, rot, pad...

// ---- Kernel A: score + has + per-bn params (one wave per bn) ----
__global__ __launch_bounds__(256)
void prep_kernel(const float* __restrict__ boxes,
                 const float* __restrict__ gt_boxes,
                 const int*   __restrict__ pos_flag,
                 const int*   __restrict__ gt_id,
                 float* __restrict__ score,
                 float* __restrict__ params)
{
    const int wave = threadIdx.x >> 6;
    const int lane = threadIdx.x & 63;
    const int bn   = blockIdx.x * 4 + wave;   // grid = 1024 blocks
    const int b    = bn >> 10;

    const float4 bx = *reinterpret_cast<const float4*>(boxes + (size_t)bn * 4);
    const int gid = gt_id[bn];
    const float* g = gt_boxes + ((size_t)b * M + gid) * 14;
    const bool valid = (g[6] != 0.0f) && (pos_flag[bn] > 0);

    // identical float-op order to the round-1 passing kernel
    const float cx = 0.5f * (bx.x + bx.z);
    const float cy = 0.5f * (bx.y + bx.w);
    const float hw = 0.5f * (bx.z - bx.x) * EXPAND;
    const float hh = 0.5f * (bx.w - bx.y) * EXPAND;
    const float ex1 = cx - hw, ey1 = cy - hh;
    const float ex2 = cx + hw, ey2 = cy + hh;
    const float sx = (float)W / (ex2 - ex1 + 1.0f);
    const float sy = (float)H / (ey2 - ey1 + 1.0f);
    const float kx = (g[4] - ex1) * sx;
    const float ky = (g[5] - ey1) * sy;

    bool any2 = false;
    float* srow = score + (size_t)bn * HW;
#pragma unroll
    for (int i = 0; i < 16; ++i) {
        const int cell = i * 64 + lane;       // coalesced 256B runs
        const int gy = cell >> 5, gx = cell & 31;
        const float dx  = (float)gx + 0.5f - kx;
        const float dy  = (float)gy + 0.5f - ky;
        const float dy2 = dy * dy;
        const float s   = expf(-((dx * dx + dy2) / TWO_SIG2));
        srow[cell] = s;
        any2 |= (s >= THR2);
    }
    const bool has = __any(any2) && valid;

    if (lane == 0) {
        float4* P = reinterpret_cast<float4*>(params + (size_t)bn * 16);
        P[0] = make_float4(kx, ky, valid ? 1.0f : 0.0f, has ? 1.0f : 0.0f);
        P[1] = make_float4(g[12], g[7], g[8], g[9]);   // depth, d0, d1, d2
        P[2] = make_float4(g[13], 0.0f, 0.0f, 0.0f);   // rot
        P[3] = make_float4(0.0f, 0.0f, 0.0f, 0.0f);
    }
}

// ---- Kernel B: fill-style dense-front streaming writer ----
// Output = 81920 chunks of 4 KB; chunk -> (group, bn, c) decode, all uniform.
// Groups (chunk counts): cls 4096 | clsw 4096 | reg2d 8192 | reg2dw 8192 |
// reg3d 8192 | reg3dw 8192 | depth 4096 | depthw 4096 | dim 12288 |
// dimw 12288 | rot 4096 | rotw 4096
__global__ __launch_bounds__(256)
void stream_kernel(const float* __restrict__ score,
                   const float* __restrict__ params,
                   float* __restrict__ out)
{
    const int tid = threadIdx.x;
    const int gy  = tid >> 3;
    const int gx0 = (tid & 7) * 4;

    for (int it = 0; it < ITERS; ++it) {
        const int chunk = blockIdx.x + it * GRID_B;   // dense 8 MiB front

        // ---- uniform group decode (ladder of scalar compares) ----
        int grp = 0;
        if (chunk >= 4096)  grp = 1;
        if (chunk >= 8192)  grp = 2;
        if (chunk >= 16384) grp = 3;
        if (chunk >= 24576) grp = 4;
        if (chunk >= 32768) grp = 5;
        if (chunk >= 40960) grp = 6;
        if (chunk >= 45056) grp = 7;
        if (chunk >= 49152) grp = 8;
        if (chunk >= 61440) grp = 9;
        if (chunk >= 73728) grp = 10;
        if (chunk >= 77824) grp = 11;

        // per-group constants: start, k
        int start, k;
        switch (grp) {
            case 0:  start = 0;     k = 1; break;
            case 1:  start = 4096;  k = 1; break;
            case 2:  start = 8192;  k = 2; break;
            case 3:  start = 16384; k = 2; break;
            case 4:  start = 24576; k = 2; break;
            case 5:  start = 32768; k = 2; break;
            case 6:  start = 40960; k = 1; break;
            case 7:  start = 45056; k = 1; break;
            case 8:  start = 49152; k = 3; break;
            case 9:  start = 61440; k = 3; break;
            case 10: start = 73728; k = 1; break;
            default: start = 77824; k = 1; break;
        }
        const int rel = chunk - start;
        int bn, c;
        if (k == 1)      { bn = rel;                 c = 0; }
        else if (k == 2) { bn = rel >> 1;            c = rel & 1; }
        else             { bn = (unsigned)rel / 3u;  c = rel - 3 * bn; }

        // ---- per-bn params (uniform address -> scalar loads, L2-hot) ----
        const float4 p0 = *reinterpret_cast<const float4*>(params + (size_t)bn * 16);
        const float4 p1 = *reinterpret_cast<const float4*>(params + (size_t)bn * 16 + 4);
        const float4 p2 = *reinterpret_cast<const float4*>(params + (size_t)bn * 16 + 8);
        const float kx = p0.x, ky = p0.y, validf = p0.z, hasf = p0.w;

        // mode: 0=a*f3 1=offx*f2 2=offy*f2 3=offx*f3 4=offy*f3 5=f2 6=cls 7=clsw 8=f3
        int mode; float a = 1.0f;
        switch (grp) {
            case 0:  mode = 6; break;
            case 1:  mode = 7; break;
            case 2:  mode = c ? 2 : 1; break;
            case 3:  mode = 5; break;
            case 4:  mode = c ? 4 : 3; break;
            case 5:  mode = 8; break;
            case 6:  mode = 0; a = p1.x; break;                            // depth
            case 7:  mode = 8; break;
            case 8:  mode = 0; a = (c == 0) ? p1.y : (c == 1 ? p1.z : p1.w); break; // dims
            case 9:  mode = 8; break;
            case 10: mode = 0; a = p2.x; break;                            // rot
            default: mode = 8; break;
        }

        // ---- score row (coalesced float4, L2/MALL-hot) ----
        const float4 sv = *reinterpret_cast<const float4*>(
            score + (size_t)bn * HW + (size_t)tid * 4);

        const float offy = ky - (float)gy;
        float4 v;
#pragma unroll
        for (int j = 0; j < 4; ++j) {
            const float s  = (&sv.x)[j];
            const float f2 = (s >= THR2) ? validf : 0.0f;
            const float f3 = (s >= THR3) ? validf : 0.0f;
            const float offx = kx - (float)(gx0 + j);
            float val;
            switch (mode) {
                case 0:  val = a * f3;                       break;
                case 1:  val = offx * f2;                    break;
                case 2:  val = offy * f2;                    break;
                case 3:  val = offx * f3;                    break;
                case 4:  val = offy * f3;                    break;
                case 5:  val = f2;                           break;
                case 6:  val = (hasf != 0.0f) ? s : -1.0f;   break;
                case 7:  val = hasf;                         break;
                default: val = f3;                           break;
            }
            (&v.x)[j] = val;
        }

        *reinterpret_cast<float4*>(out + (size_t)chunk * HW + (size_t)tid * 4) = v;
    }
}

extern "C" void kernel_launch(void* const* d_in, const int* in_sizes, int n_in,
                              void* d_out, int out_size, void* d_ws, size_t ws_size,
                              hipStream_t stream) {
    const float* boxes    = (const float*)d_in[0];
    const float* gt_boxes = (const float*)d_in[1];
    const int*   pos_flag = (const int*)d_in[2];
    const int*   gt_id    = (const int*)d_in[3];
    float*       out      = (float*)d_out;
    float*       score    = (float*)d_ws;            // 16 MiB
    float*       params   = score + S;               // 256 KiB

    prep_kernel<<<dim3(BN / 4), dim3(256), 0, stream>>>(
        boxes, gt_boxes, pos_flag, gt_id, score, params);

    stream_kernel<<<dim3(GRID_B), dim3(256), 0, stream>>>(
        score, params, out);
}

// Round 6
// 336.221 us; speedup vs baseline: 1.1233x; 1.1233x over previous
//
#include <hip/hip_runtime.h>

// Problem constants (from reference)
constexpr int B = 4, N = 1024, M = 64, H = 32, W = 32;
constexpr int HW = H * W;                       // 1024
constexpr size_t S = (size_t)B * N * HW;        // per-channel plane stride (floats)
constexpr float EXPAND   = 1.2f;
constexpr float TWO_SIG2 = 2.0f * 1.6f * 1.6f;  // 5.12
constexpr float THR2 = 0.6f;                    // GAUSS_THR
constexpr float THR3 = 0.5f;                    // GAUSS_3D_THR == GAUSS_DEPTH_THR

// One 64-lane wave per bn. Lane owns, for each q-group (q=0..3), the 4 cells
// [q*256 + lane*4, +4) -> store address base + q*1024B + lane*16B (unit stride,
// full cache lines). 80 independent float4 stores per wave, issued in 4 bursts
// of 20 with no intervening memory reads (max store MLP — the R1 property that
// every other layout lost).

__global__ __launch_bounds__(64)
void rcnn3d_wave_kernel(const float* __restrict__ boxes,     // (B,N,4)
                        const float* __restrict__ gt_boxes,  // (B,M,14)
                        const int*   __restrict__ pos_flag,  // (B,N)
                        const int*   __restrict__ gt_id,     // (B,N)
                        float* __restrict__ out)
{
    const int bn   = blockIdx.x;       // uniform -> everything per-bn is SGPR
    const int b    = bn >> 10;
    const int lane = threadIdx.x;      // 0..63

    // ---- per-bn scalars (uniform addresses -> s_load, L1/L2-hot) ----
    const float4 bx = *reinterpret_cast<const float4*>(boxes + (size_t)bn * 4);
    const int gid = gt_id[bn];
    const float* g = gt_boxes + ((size_t)b * M + gid) * 14;
    const bool valid = (g[6] != 0.0f) && (pos_flag[bn] > 0);
    const float depth = g[12], d0 = g[7], d1 = g[8], d2 = g[9], rot = g[13];

    // identical float-op order to the round-1 passing kernel
    const float cx = 0.5f * (bx.x + bx.z);
    const float cy = 0.5f * (bx.y + bx.w);
    const float hw = 0.5f * (bx.z - bx.x) * EXPAND;
    const float hh = 0.5f * (bx.w - bx.y) * EXPAND;
    const float ex1 = cx - hw, ey1 = cy - hh;
    const float ex2 = cx + hw, ey2 = cy + hh;
    const float sx = (float)W / (ex2 - ex1 + 1.0f);
    const float sy = (float)H / (ey2 - ey1 + 1.0f);
    const float kx = (g[4] - ex1) * sx;
    const float ky = (g[5] - ey1) * sy;

    const int colBase = (lane & 7) * 4;   // column of j=0
    const int rowOff  = lane >> 3;        // row within q-group

    // ---- phase 1: all 16 scores; s[q*4+j] = score(cell q*256 + lane*4 + j) ----
    float s[16];
    bool any2 = false;
#pragma unroll
    for (int q = 0; q < 4; ++q) {
        const int gy = q * 8 + rowOff;
        const float dy  = (float)gy + 0.5f - ky;
        const float dy2 = dy * dy;
#pragma unroll
        for (int j = 0; j < 4; ++j) {
            const float dx = (float)(colBase + j) + 0.5f - kx;
            const float v  = expf(-((dx * dx + dy2) / TWO_SIG2));
            s[q * 4 + j] = v;
            any2 |= (v >= THR2);
        }
    }
    const bool  has    = __any(any2) && valid;   // wave-level, no LDS/barrier
    const float validf = valid ? 1.0f : 0.0f;

    // ---- phase 2: 4 bursts x 20 independent full-line float4 stores ----
    const size_t bn1 = (size_t)bn * HW;
    const size_t bn2 = (size_t)bn * 2 * HW;
    const size_t bn3 = (size_t)bn * 3 * HW;

#pragma unroll
    for (int q = 0; q < 4; ++q) {
        const int gy = q * 8 + rowOff;
        const float offy = ky - (float)gy;

        float4 v_cls, v_clsw, v_rx2, v_ry2, v_w2, v_rx3, v_ry3, v_w3;
        float4 v_dep, v_d0, v_d1, v_d2, v_rot;
#pragma unroll
        for (int j = 0; j < 4; ++j) {
            const float sv = s[q * 4 + j];
            const float f2 = (sv >= THR2) ? validf : 0.0f;
            const float f3 = (sv >= THR3) ? validf : 0.0f;
            const float offx = kx - (float)(colBase + j);
            (&v_cls.x)[j]  = has ? sv : -1.0f;
            (&v_clsw.x)[j] = has ? 1.0f : 0.0f;
            (&v_rx2.x)[j]  = offx * f2;
            (&v_ry2.x)[j]  = offy * f2;
            (&v_w2.x)[j]   = f2;
            (&v_rx3.x)[j]  = offx * f3;
            (&v_ry3.x)[j]  = offy * f3;
            (&v_w3.x)[j]   = f3;
            (&v_dep.x)[j]  = depth * f3;
            (&v_d0.x)[j]   = d0 * f3;
            (&v_d1.x)[j]   = d1 * f3;
            (&v_d2.x)[j]   = d2 * f3;
            (&v_rot.x)[j]  = rot * f3;
        }

        const size_t cell = (size_t)q * 256 + (size_t)lane * 4;
        auto st = [&](size_t ofs, const float4& v) {
            *reinterpret_cast<float4*>(out + ofs + cell) = v;
        };

        st( 0 * S + bn1,          v_cls);
        st( 1 * S + bn1,          v_clsw);
        st( 2 * S + bn2,          v_rx2);
        st( 2 * S + bn2 + HW,     v_ry2);
        st( 4 * S + bn2,          v_w2);
        st( 4 * S + bn2 + HW,     v_w2);
        st( 6 * S + bn2,          v_rx3);
        st( 6 * S + bn2 + HW,     v_ry3);
        st( 8 * S + bn2,          v_w3);
        st( 8 * S + bn2 + HW,     v_w3);
        st(10 * S + bn1,          v_dep);
        st(11 * S + bn1,          v_w3);
        st(12 * S + bn3,          v_d0);
        st(12 * S + bn3 + HW,     v_d1);
        st(12 * S + bn3 + 2*HW,   v_d2);
        st(15 * S + bn3,          v_w3);
        st(15 * S + bn3 + HW,     v_w3);
        st(15 * S + bn3 + 2*HW,   v_w3);
        st(18 * S + bn1,          v_rot);
        st(19 * S + bn1,          v_w3);
    }
}

extern "C" void kernel_launch(void* const* d_in, const int* in_sizes, int n_in,
                              void* d_out, int out_size, void* d_ws, size_t ws_size,
                              hipStream_t stream) {
    const float* boxes    = (const float*)d_in[0];
    const float* gt_boxes = (const float*)d_in[1];
    const int*   pos_flag = (const int*)d_in[2];
    const int*   gt_id    = (const int*)d_in[3];
    float*       out      = (float*)d_out;

    rcnn3d_wave_kernel<<<dim3(B * N), dim3(64), 0, stream>>>(
        boxes, gt_boxes, pos_flag, gt_id, out);
}